// Round 2
// baseline (2404.919 us; speedup 1.0000x reference)
//
#include <hip/hip_runtime.h>

#define B_ 16
#define N_ 4096
#define C_ 64
#define S_ 1024
#define K_ 32
#define CIN 67
#define O3 128
#define M_ (B_*S_*K_)   /* 524288 */
#define NBKT 64
#define EPS_ 1e-5f

__device__ __forceinline__ float sqd3(float dx, float dy, float dz){
  // match reference: ((dx*dx + dy*dy) + dz*dz), no fma contraction
  return __fadd_rn(__fadd_rn(__fmul_rn(dx,dx),__fmul_rn(dy,dy)),__fmul_rn(dz,dz));
}

// ---------------- FPS: one block per batch ----------------
__global__ __launch_bounds__(1024) void fps_kernel(const float* __restrict__ xyz,
    float* __restrict__ nxt /*B,S,3*/, float* __restrict__ out_xyz /*B,3,S*/){
  int b = blockIdx.x;
  const float* xb = xyz + (size_t)b*3*N_;
  __shared__ float xs[3*N_];
  __shared__ float rv[16]; __shared__ int ri[16];
  __shared__ int s_last;
  int tid = threadIdx.x;
  for (int i=tid;i<3*N_;i+=1024) xs[i]=xb[i];
  __syncthreads();
  float dist[4];
  #pragma unroll
  for (int j=0;j<4;j++) dist[j]=1e10f;
  int last = 0;
  for (int it=0; ; ++it){
    if (tid<3){
      float v = xs[tid*N_+last];
      nxt[(b*S_+it)*3+tid]=v;
      out_xyz[(size_t)b*3*S_ + (size_t)tid*S_ + it]=v;
    }
    if (it==S_-1) break;
    float lx=xs[last], ly=xs[N_+last], lz=xs[2*N_+last];
    float bv=-1.0f; int bi=0;
    #pragma unroll
    for (int j=0;j<4;j++){
      int n = j*1024+tid;
      float dx=xs[n]-lx, dy=xs[N_+n]-ly, dz=xs[2*N_+n]-lz;
      float d = sqd3(dx,dy,dz);
      float dn = fminf(dist[j], d);
      dist[j]=dn;
      if (dn > bv){ bv=dn; bi=n; }   // j ascending => keeps smallest n on ties
    }
    #pragma unroll
    for (int off=32; off>0; off>>=1){
      float v2 = __shfl_down(bv, off);
      int   i2 = __shfl_down(bi, off);
      if (v2 > bv || (v2==bv && i2<bi)){ bv=v2; bi=i2; }
    }
    int w = tid>>6;
    if ((tid&63)==0){ rv[w]=bv; ri[w]=bi; }
    __syncthreads();
    if (tid<64){
      if (tid<16){ bv=rv[tid]; bi=ri[tid]; } else { bv=-1e30f; bi=0x7fffffff; }
      #pragma unroll
      for (int off=8; off>0; off>>=1){
        float v2=__shfl_down(bv,off); int i2=__shfl_down(bi,off);
        if (v2 > bv || (v2==bv && i2<bi)){ bv=v2; bi=i2; }
      }
      if (tid==0) s_last = bi;
    }
    __syncthreads();
    last = s_last;
  }
}

// ---------------- Ball query: one wave per query ----------------
__global__ __launch_bounds__(256) void ballq_kernel(const float* __restrict__ xyz,
    const float* __restrict__ nxt, int* __restrict__ idx){
  const float R2 = (float)(0.1*0.1);   // matches JAX f64->f32 cast of radius*radius
  int lane = threadIdx.x & 63;
  int q = (blockIdx.x<<2) + (threadIdx.x>>6);
  int b = q >> 10;
  const float* xb = xyz + (size_t)b*3*N_;
  float qx = nxt[q*3+0], qy=nxt[q*3+1], qz=nxt[q*3+2];
  int* out = idx + (size_t)q*K_;
  int filled = 0; int first = N_;
  for (int n0=0; n0<N_ && filled<K_; n0+=64){
    int n = n0+lane;
    float dx = xb[n]-qx, dy=xb[N_+n]-qy, dz=xb[2*N_+n]-qz;
    float d = sqd3(dx,dy,dz);
    bool inb = (d <= R2);
    unsigned long long m = __ballot(inb);
    if (inb){
      int pos = filled + __popcll(m & ((1ull<<lane)-1ull));
      if (pos < K_) out[pos] = n;
    }
    if (first==N_ && m) first = n0 + (__ffsll((unsigned long long)m)-1);
    filled += __popcll(m);
  }
  if (filled < K_){
    if (first==N_) first = N_-1;  // unreachable (query point is in the set)
    for (int t = filled + lane; t < K_; t += 64) out[t] = first;
  }
}

// ---------------- transpose points (B,64,N) -> (B,N,64) ----------------
__global__ __launch_bounds__(256) void transpose_kernel(const float* __restrict__ pts,
    float* __restrict__ pts_t){
  __shared__ float t[64][65];
  int b = blockIdx.x >> 6;
  int n0 = (blockIdx.x & 63) << 6;
  const float* in = pts + (size_t)b*C_*N_;
  float* out = pts_t + (size_t)b*N_*C_;
  int tid=threadIdx.x;
  for (int i=tid;i<64*64;i+=256){ int c=i>>6, x=i&63; t[c][x]=in[(size_t)c*N_ + n0 + x]; }
  __syncthreads();
  for (int i=tid;i<64*64;i+=256){ int n=i>>6, c=i&63; out[(size_t)(n0+n)*C_ + c]=t[c][n]; }
}

// ---------------- layer1: gather + (67->64) + stats ----------------
__global__ __launch_bounds__(256) void layer1_kernel(const float* __restrict__ xyz,
    const float* __restrict__ pts_t, const float* __restrict__ nxt,
    const int* __restrict__ idx, const float* __restrict__ W1,
    float* __restrict__ y1, float* __restrict__ stats){
  int q = blockIdx.x; int b = q>>10;
  __shared__ float Ws[CIN][64];
  __shared__ float xin[32][68];
  __shared__ float yt[32][64];
  __shared__ int sidx[32];
  __shared__ float ctr[3];
  int tid=threadIdx.x;
  for (int i=tid;i<CIN*64;i+=256){ int c=i>>6,o=i&63; Ws[c][o]=W1[c + o*CIN]; }
  if (tid<32) sidx[tid]=idx[(size_t)q*K_+tid];
  if (tid<3)  ctr[tid]=nxt[q*3+tid];
  __syncthreads();
  int r=tid>>3, l8=tid&7;
  int j=sidx[r];
  const float* prow = pts_t + ((size_t)b*N_ + j)*C_;
  float4 a = *(const float4*)(prow + l8*8);
  float4 c4 = *(const float4*)(prow + l8*8 + 4);
  int base = 3 + l8*8;
  xin[r][base+0]=a.x; xin[r][base+1]=a.y; xin[r][base+2]=a.z; xin[r][base+3]=a.w;
  xin[r][base+4]=c4.x; xin[r][base+5]=c4.y; xin[r][base+6]=c4.z; xin[r][base+7]=c4.w;
  if (l8==0){
    const float* xbb = xyz + (size_t)b*3*N_;
    xin[r][0]=xbb[j]        - ctr[0];
    xin[r][1]=xbb[N_+j]     - ctr[1];
    xin[r][2]=xbb[2*N_+j]   - ctr[2];
  }
  __syncthreads();
  float acc[8];
  #pragma unroll
  for (int i=0;i<8;i++) acc[i]=0.f;
  for (int c=0;c<CIN;c++){
    float xv = xin[r][c];
    #pragma unroll
    for (int i=0;i<8;i++) acc[i] = fmaf(xv, Ws[c][l8*8+i], acc[i]);
  }
  float* yrow = y1 + (((size_t)q*K_ + r)*64) + l8*8;
  float4 o0 = {acc[0],acc[1],acc[2],acc[3]};
  float4 o1 = {acc[4],acc[5],acc[6],acc[7]};
  *(float4*)yrow = o0; *(float4*)(yrow+4) = o1;
  #pragma unroll
  for (int i=0;i<8;i++) yt[r][l8*8+i]=acc[i];
  __syncthreads();
  if (tid<64){
    float sum=0.f, ss=0.f;
    #pragma unroll
    for (int rr=0;rr<32;rr++){ float v=yt[rr][tid]; sum+=v; ss=fmaf(v,v,ss); }
    int bkt = q & (NBKT-1);
    atomicAdd(&stats[((size_t)bkt*2+0)*128+tid], sum);
    atomicAdd(&stats[((size_t)bkt*2+1)*128+tid], ss);
  }
}

// ---------------- layer2: bn1+relu + (64->64) + stats; writes y2 IN-PLACE over y1 -------
// Safe: each block reads only its own 32x64 tile (all global reads precede the barrier),
// then overwrites the same tile after the barrier.
__global__ __launch_bounds__(256) void layer2_kernel(float* __restrict__ ybuf,
    const float* __restrict__ W2, const float* __restrict__ st1,
    float* __restrict__ stats){
  int q = blockIdx.x;
  __shared__ float Ws[64][64];
  __shared__ float xin[32][65];
  __shared__ float yt[32][64];
  __shared__ float sc[64], tc[64];
  int tid=threadIdx.x;
  for (int i=tid;i<64*64;i+=256){ int c=i>>6,o=i&63; Ws[c][o]=W2[c + o*64]; }
  if (tid<64){ sc[tid]=st1[tid]; tc[tid]=st1[128+tid]; }
  __syncthreads();                         // sc/tc visible to all before use
  float* yrow = ybuf + (size_t)q*K_*64;
  for (int i=tid;i<K_*64;i+=256){
    int r=i>>6,c=i&63;
    float v = fmaf(yrow[i], sc[c], tc[c]);
    xin[r][c] = v>0.f ? v : 0.f;
  }
  __syncthreads();
  int r=tid>>3, l8=tid&7;
  float acc[8];
  #pragma unroll
  for (int i=0;i<8;i++) acc[i]=0.f;
  for (int c=0;c<64;c++){
    float xv = xin[r][c];
    #pragma unroll
    for (int i=0;i<8;i++) acc[i] = fmaf(xv, Ws[c][l8*8+i], acc[i]);
  }
  float* orow = yrow + (size_t)r*64 + l8*8;
  float4 o0 = {acc[0],acc[1],acc[2],acc[3]};
  float4 o1 = {acc[4],acc[5],acc[6],acc[7]};
  *(float4*)orow = o0; *(float4*)(orow+4) = o1;
  #pragma unroll
  for (int i=0;i<8;i++) yt[r][l8*8+i]=acc[i];
  __syncthreads();
  if (tid<64){
    float sum=0.f, ss=0.f;
    #pragma unroll
    for (int rr=0;rr<32;rr++){ float v=yt[rr][tid]; sum+=v; ss=fmaf(v,v,ss); }
    int bkt = q & (NBKT-1);
    atomicAdd(&stats[((size_t)bkt*2+0)*128+tid], sum);
    atomicAdd(&stats[((size_t)bkt*2+1)*128+tid], ss);
  }
}

// ---------------- layer3: bn2+relu + (64->128) + max_k + stats (y3 never stored) --------
__global__ __launch_bounds__(256) void layer3_kernel(const float* __restrict__ y2,
    const float* __restrict__ W3, const float* __restrict__ st2,
    float* __restrict__ m3, float* __restrict__ stats){
  int q=blockIdx.x;
  __shared__ float Ws[64][O3];
  __shared__ float xin[32][65];
  __shared__ float yt[32][O3];
  __shared__ float sc[64], tc[64];
  int tid=threadIdx.x;
  for (int i=tid;i<64*O3;i+=256){ int c=i>>7,o=i&127; Ws[c][o]=W3[c + o*64]; }
  if (tid<64){ sc[tid]=st2[tid]; tc[tid]=st2[128+tid]; }
  __syncthreads();
  const float* yrow = y2 + (size_t)q*K_*64;
  for (int i=tid;i<K_*64;i+=256){
    int r=i>>6,c=i&63;
    float v = fmaf(yrow[i], sc[c], tc[c]);
    xin[r][c] = v>0.f ? v : 0.f;
  }
  __syncthreads();
  int r=tid>>3, l8=tid&7;
  float acc[16];
  #pragma unroll
  for(int i=0;i<16;i++) acc[i]=0.f;
  for (int c=0;c<64;c++){
    float xv=xin[r][c];
    #pragma unroll
    for (int i=0;i<16;i++) acc[i]=fmaf(xv, Ws[c][i*8+l8], acc[i]);  // oc = i*8+l8 (bank-spread)
  }
  #pragma unroll
  for (int i=0;i<16;i++) yt[r][i*8+l8]=acc[i];
  __syncthreads();
  if (tid<O3){
    float sum=0.f, ss=0.f, mx=-1e30f;
    #pragma unroll
    for (int rr=0;rr<32;rr++){ float v=yt[rr][tid]; sum+=v; ss=fmaf(v,v,ss); mx=fmaxf(mx,v); }
    m3[(size_t)q*O3+tid]=mx;
    int bkt=q&(NBKT-1);
    atomicAdd(&stats[((size_t)bkt*2+0)*128+tid], sum);
    atomicAdd(&stats[((size_t)bkt*2+1)*128+tid], ss);
  }
}

// ---------------- BN finalize ----------------
__global__ void finalize_kernel(const float* __restrict__ stats, const float* __restrict__ g,
    const float* __restrict__ bias, float* __restrict__ st, int Cc){
  int o=threadIdx.x; if (o>=Cc) return;
  float sum=0.f, ss=0.f;
  for (int k=0;k<NBKT;k++){ sum+=stats[((size_t)k*2+0)*128+o]; ss+=stats[((size_t)k*2+1)*128+o]; }
  const float invM = 1.0f/(float)M_;
  float mu = sum*invM;
  float var = ss*invM - mu*mu;
  if (var<0.f) var=0.f;
  float s = g[o] / sqrtf(var+EPS_);
  st[o]=s; st[128+o]=bias[o]-mu*s;
}

// ---------------- epilogue: bn3+relu applied to max, transpose to (B,128,S) ------------
__global__ __launch_bounds__(256) void out_kernel(const float* __restrict__ m3,
    const float* __restrict__ st3, float* __restrict__ out){
  int i = blockIdx.x*256 + threadIdx.x;   // over B*128*1024
  int s = i & 1023;
  int o = (i>>10) & 127;
  int b = i>>17;
  float v = m3[((size_t)b*S_+s)*O3+o];
  v = fmaf(v, st3[o], st3[128+o]);
  out[i] = v>0.f ? v : 0.f;
}

extern "C" void kernel_launch(void* const* d_in, const int* in_sizes, int n_in,
                              void* d_out, int out_size, void* d_ws, size_t ws_size,
                              hipStream_t stream){
  const float* xyz = (const float*)d_in[0];
  const float* pts = (const float*)d_in[1];
  const float* W1  = (const float*)d_in[2];
  const float* g1  = (const float*)d_in[3];
  const float* b1  = (const float*)d_in[4];
  const float* W2  = (const float*)d_in[5];
  const float* g2  = (const float*)d_in[6];
  const float* b2  = (const float*)d_in[7];
  const float* W3  = (const float*)d_in[8];
  const float* g3  = (const float*)d_in[9];
  const float* b3  = (const float*)d_in[10];
  float* out = (float*)d_out;

  char* ws = (char*)d_ws;
  size_t off=0;
  auto alloc=[&](size_t bytes)->char*{ char* p=ws+off; off += (bytes+255)&~255ull; return p; };
  float* nxt     = (float*)alloc((size_t)B_*S_*3*4);            // 192 KB
  int*   idx     = (int*)  alloc((size_t)B_*S_*K_*4);           // 2 MB
  float* pts_t   = (float*)alloc((size_t)B_*N_*C_*4);           // 16.8 MB
  float* stats   = (float*)alloc((size_t)3*NBKT*2*128*4);       // 192 KB
  float* st1     = (float*)alloc(256*4);
  float* st2     = (float*)alloc(256*4);
  float* st3     = (float*)alloc(256*4);
  float* m3      = (float*)alloc((size_t)B_*S_*O3*4);           // 8.4 MB
  float* ybuf    = (float*)alloc((size_t)M_*64*4);              // 134 MB (y1, then y2 in-place)
  // total ~162 MB (was ~296 MB -> suspected d_ws overflow -> GPU fault)

  float* stats1 = stats;
  float* stats2 = stats + (size_t)NBKT*2*128;
  float* stats3 = stats + (size_t)2*NBKT*2*128;

  hipMemsetAsync(stats, 0, (size_t)3*NBKT*2*128*4, stream);
  hipLaunchKernelGGL(transpose_kernel, dim3(B_*64), dim3(256), 0, stream, pts, pts_t);
  hipLaunchKernelGGL(fps_kernel,   dim3(B_),      dim3(1024), 0, stream, xyz, nxt, out);
  hipLaunchKernelGGL(ballq_kernel, dim3(B_*S_/4), dim3(256),  0, stream, xyz, nxt, idx);
  hipLaunchKernelGGL(layer1_kernel,dim3(B_*S_),   dim3(256),  0, stream, xyz, pts_t, nxt, idx, W1, ybuf, stats1);
  hipLaunchKernelGGL(finalize_kernel, dim3(1), dim3(128), 0, stream, stats1, g1, b1, st1, 64);
  hipLaunchKernelGGL(layer2_kernel,dim3(B_*S_),   dim3(256),  0, stream, ybuf, W2, st1, stats2);
  hipLaunchKernelGGL(finalize_kernel, dim3(1), dim3(128), 0, stream, stats2, g2, b2, st2, 64);
  hipLaunchKernelGGL(layer3_kernel,dim3(B_*S_),   dim3(256),  0, stream, ybuf, W3, st2, m3, stats3);
  hipLaunchKernelGGL(finalize_kernel, dim3(1), dim3(128), 0, stream, stats3, g3, b3, st3, 128);
  hipLaunchKernelGGL(out_kernel, dim3((B_*O3*S_)/256), dim3(256), 0, stream, m3, st3, out + (size_t)B_*3*S_);
}